// Round 5
// baseline (244.761 us; speedup 1.0000x reference)
//
#include <hip/hip_runtime.h>
#include <stdint.h>

// VQ-VAE vector quantizer — fp32, NCHW input [64,64,32,32], emb [1024,64].
// Bit-exact replication of numpy's fp32 expression tree (round 3/4 passed,
// absmax 0.0):
//   d_k = fp32( fp32(A - 2*G_k) + C_k )
//   A,C = np-pairwise sums of squares; G_k = sequential fp32 FMA over d.
//
// Perf history:
//  r3: LDS broadcast path, 354 us — LDS-read-pipe bound (13 cyc/b128/CU).
//  r4: SMEM (wave-uniform s_load) path, 173 us — but x[64] was demoted to
//      scratch (VGPR=40, WRITE_SIZE 82 MB) because the epilogue indexed the
//      register array dynamically (x[db+j]).
//  r5 (this): epilogue reloads x from global (no dynamic register-array
//      indexing anywhere) -> x stays in VGPRs; vq_fin fused via ticket.
constexpr int KCODES = 1024;
constexpr int DDIM   = 64;
constexpr int HW     = 1024;
constexpr int NPTS   = 65536;

constexpr int OUT_Q    = 0;         // 4194304: straight-through fwd (NCHW)
constexpr int OUT_IDX  = 4194304;   // 65536:  encodings as float
constexpr int OUT_LOSS = 4259840;   // 1
constexpr int OUT_NLL  = 4259841;   // 1

// ws (floats): [0..1023] C_k ; [1024] loss accumulator ; [1025] ticket (u32)

__device__ __forceinline__ float np_pairwise_sumsq64(const float* a) {
    float r[8];
    #pragma unroll
    for (int j = 0; j < 8; ++j) r[j] = __fmul_rn(a[j], a[j]);
    #pragma unroll
    for (int i = 8; i < 64; i += 8)
        #pragma unroll
        for (int j = 0; j < 8; ++j)
            r[j] = __fadd_rn(r[j], __fmul_rn(a[i + j], a[i + j]));
    return __fadd_rn(__fadd_rn(__fadd_rn(r[0], r[1]), __fadd_rn(r[2], r[3])),
                     __fadd_rn(__fadd_rn(r[4], r[5]), __fadd_rn(r[6], r[7])));
}

__global__ void vq_pre(const float* __restrict__ emb, float* __restrict__ ws) {
    int k = blockIdx.x * blockDim.x + threadIdx.x;
    if (k == 0) { ws[KCODES] = 0.0f; ((unsigned*)ws)[KCODES + 1] = 0u; }
    if (k < KCODES) {
        float row[DDIM];
        const float4* src = (const float4*)(emb + (size_t)k * DDIM);
        #pragma unroll
        for (int j = 0; j < 16; ++j) ((float4*)row)[j] = src[j];
        ws[k] = np_pairwise_sumsq64(row);          // C_k
    }
}

// Block: 256 threads = 4 waves; wave w scans codes [256w, 256w+256) for the
// block's 64 points (point = blockIdx*64 + lane). Grid 1024 -> 4 blocks/CU.
__global__ __launch_bounds__(256, 4) void vq_main(
        const float* __restrict__ inp,    // [64][64][1024] fp32 NCHW
        const float* __restrict__ emb_,   // [1024][64] fp32
        const float* __restrict__ cws_,   // C_k
        float*       __restrict__ loss_acc,
        unsigned*    __restrict__ ticket,
        float*       __restrict__ out,
        int          nblocks)
{
    const float* emb = (const float*)__builtin_assume_aligned(emb_, 256);
    const float* cws = (const float*)__builtin_assume_aligned(cws_, 256);

    __shared__ float rbest[256];
    __shared__ int   rbi[256];
    __shared__ int   sbi[64];
    __shared__ float sred[4];

    const int tid  = threadIdx.x;
    const int lane = tid & 63;
    const int wave = __builtin_amdgcn_readfirstlane(tid >> 6);  // uniform

    const int n  = blockIdx.x * 64 + lane;   // point id
    const int b  = n >> 10;
    const int hw = n & (HW - 1);

    // x[d] = inp[b][d][hw]; lanes -> consecutive hw => 256B coalesced per d.
    // NOTE: x[] is only ever indexed with compile-time constants (keeps it
    // in VGPRs — dynamic indexing demotes the array to scratch).
    const float* xin = inp + (size_t)b * DDIM * HW + hw;
    float x[DDIM];
    #pragma unroll
    for (int d = 0; d < DDIM; ++d) x[d] = xin[(size_t)d * HW];

    const float A = np_pairwise_sumsq64(x);

    // Scan this wave's 256-code slice; e-row address is wave-uniform =>
    // scalar loads (SMEM) feeding v_fma with SGPR operand. Sequential fp32
    // FMA chain over d (bit-exact vs BLAS sgemm microkernel order).
    const int    k0 = wave * 256;
    const float* eb = emb + (size_t)k0 * DDIM;
    float best = 3.0e38f;
    int   bi   = k0;

    #pragma unroll 1
    for (int k = 0; k < 256; ++k) {
        const float* er = eb + (size_t)k * DDIM;   // uniform
        float g = 0.f;
        #pragma unroll
        for (int d = 0; d < DDIM; ++d) g = fmaf(x[d], er[d], g);
        float dk = __fadd_rn(__fsub_rn(A, __fmul_rn(2.0f, g)), cws[k0 + k]);
        if (dk < best) { best = dk; bi = k0 + k; }  // strict < => first-min
    }

    rbest[tid] = best;
    rbi[tid]   = bi;
    __syncthreads();

    // Combine 4 slice winners per point; ascending slice + strict < keeps the
    // lowest code index on quantized ties (matches np.argmin first-index).
    if (tid < 64) {
        float bb = rbest[tid];
        int   ii = rbi[tid];
        #pragma unroll
        for (int s = 1; s < 4; ++s) {
            float c = rbest[s * 64 + tid];
            if (c < bb) { bb = c; ii = rbi[s * 64 + tid]; }
        }
        out[OUT_IDX + n] = (float)ii;
        sbi[tid] = ii;
    }
    __syncthreads();

    // Epilogue: wave w writes channels [16w,16w+16). x is RELOADED from
    // global (L1/L2-hot, coalesced) — do NOT index the x[] register array
    // with a runtime subscript.
    const int mybi = sbi[lane];
    const int db   = wave * 16;
    float q[16];
    const float4* q4 = (const float4*)(emb + (size_t)mybi * DDIM + db);
    #pragma unroll
    for (int j = 0; j < 4; ++j) ((float4*)q)[j] = q4[j];

    float* orow = out + OUT_Q + (size_t)b * DDIM * HW + hw;
    float lacc = 0.f;
    #pragma unroll
    for (int j = 0; j < 16; ++j) {
        const int d  = db + j;
        float xv     = xin[(size_t)d * HW];
        float diff   = __fsub_rn(q[j], xv);
        orow[(size_t)d * HW] = __fadd_rn(xv, diff);   // ref's x + (q - x)
        lacc = fmaf(diff, diff, lacc);
    }

    #pragma unroll
    for (int off = 32; off > 0; off >>= 1) lacc += __shfl_down(lacc, off, 64);
    if (lane == 0) sred[wave] = lacc;
    __syncthreads();

    if (tid == 0) {
        atomicAdd(loss_acc, sred[0] + sred[1] + sred[2] + sred[3]);
        __threadfence();                                  // publish loss add
        unsigned old = atomicAdd(ticket, 1u);
        if (old == (unsigned)(nblocks - 1)) {             // last block
            __threadfence();                              // acquire all adds
            float L = __hip_atomic_load(loss_acc, __ATOMIC_RELAXED,
                                        __HIP_MEMORY_SCOPE_AGENT);
            out[OUT_LOSS] = L * (1.25f / 4194304.0f);     // (1+CC)*mean
            out[OUT_NLL]  = 1.0f;
        }
    }
}

extern "C" void kernel_launch(void* const* d_in, const int* in_sizes, int n_in,
                              void* d_out, int out_size, void* d_ws, size_t ws_size,
                              hipStream_t stream) {
    const float* inp = (const float*)d_in[0];
    const float* emb = (const float*)d_in[1];
    float* out = (float*)d_out;
    float* ws  = (float*)d_ws;

    const int nblocks = NPTS / 64;   // 1024
    vq_pre<<<4, 256, 0, stream>>>(emb, ws);
    vq_main<<<nblocks, 256, 0, stream>>>(inp, emb, ws, ws + KCODES,
                                         (unsigned*)(ws + KCODES + 1), out,
                                         nblocks);
}

// Round 6
// 242.683 us; speedup vs baseline: 1.0086x; 1.0086x over previous
//
#include <hip/hip_runtime.h>
#include <stdint.h>

// VQ-VAE vector quantizer — fp32, NCHW input [64,64,32,32], emb [1024,64].
// Bit-exact replication of numpy's fp32 expression tree (r3/r4/r5 passed,
// absmax 0.0):
//   d_k = fp32( fp32(A - 2*G_k) + C_k )
//   A,C = np-pairwise sums of squares; G_k = sequential fp32 FMA over d.
//
// Perf history:
//  r3: LDS broadcast e-path, 354 us — LDS-read-pipe bound.
//  r4: SMEM e-path, 173 us — x[64] scratch-spilled (dynamic index in epilogue).
//  r5: static indices only, 192 us — but VGPR=40: LLVM REMATERIALIZED the
//      loop-invariant x loads into the k-loop (re-load per FMA), VMEM-bound.
//  r6 (this): launder x[d] through empty asm "+v" after load — compiler can
//      no longer recreate x from memory, pinning it in VGPRs. Epilogue runs
//      on wave 0 using register x[] at static indices.
constexpr int KCODES = 1024;
constexpr int DDIM   = 64;
constexpr int HW     = 1024;
constexpr int NPTS   = 65536;

constexpr int OUT_Q    = 0;         // 4194304: straight-through fwd (NCHW)
constexpr int OUT_IDX  = 4194304;   // 65536:  encodings as float
constexpr int OUT_LOSS = 4259840;   // 1
constexpr int OUT_NLL  = 4259841;   // 1

// ws (floats): [0..1023] C_k ; [1024] loss accumulator ; [1025] ticket (u32)

__device__ __forceinline__ float np_pairwise_sumsq64(const float* a) {
    float r[8];
    #pragma unroll
    for (int j = 0; j < 8; ++j) r[j] = __fmul_rn(a[j], a[j]);
    #pragma unroll
    for (int i = 8; i < 64; i += 8)
        #pragma unroll
        for (int j = 0; j < 8; ++j)
            r[j] = __fadd_rn(r[j], __fmul_rn(a[i + j], a[i + j]));
    return __fadd_rn(__fadd_rn(__fadd_rn(r[0], r[1]), __fadd_rn(r[2], r[3])),
                     __fadd_rn(__fadd_rn(r[4], r[5]), __fadd_rn(r[6], r[7])));
}

__global__ void vq_pre(const float* __restrict__ emb, float* __restrict__ ws) {
    int k = blockIdx.x * blockDim.x + threadIdx.x;
    if (k == 0) { ws[KCODES] = 0.0f; ((unsigned*)ws)[KCODES + 1] = 0u; }
    if (k < KCODES) {
        float row[DDIM];
        const float4* src = (const float4*)(emb + (size_t)k * DDIM);
        #pragma unroll
        for (int j = 0; j < 16; ++j) ((float4*)row)[j] = src[j];
        ws[k] = np_pairwise_sumsq64(row);          // C_k
    }
}

// Block: 256 threads = 4 waves; wave w scans codes [256w, 256w+256) for the
// block's 64 points (point = blockIdx*64 + lane). Grid 1024 -> 4 blocks/CU.
__global__ __launch_bounds__(256, 4) void vq_main(
        const float* __restrict__ inp,    // [64][64][1024] fp32 NCHW
        const float* __restrict__ emb_,   // [1024][64] fp32
        const float* __restrict__ cws_,   // C_k
        float*       __restrict__ loss_acc,
        unsigned*    __restrict__ ticket,
        float*       __restrict__ out,
        int          nblocks)
{
    const float* emb = (const float*)__builtin_assume_aligned(emb_, 256);
    const float* cws = (const float*)__builtin_assume_aligned(cws_, 256);

    __shared__ float rbest[256];
    __shared__ int   rbi[256];

    const int tid  = threadIdx.x;
    const int lane = tid & 63;
    const int wave = __builtin_amdgcn_readfirstlane(tid >> 6);  // uniform

    const int n  = blockIdx.x * 64 + lane;   // point id
    const int b  = n >> 10;                  // same b for the whole block
    const int hw = n & (HW - 1);

    // x[d] = inp[b][d][hw]; lanes -> consecutive hw => 256B coalesced per d.
    const float* xin = inp + (size_t)b * DDIM * HW + hw;
    float x[DDIM];
    #pragma unroll
    for (int d = 0; d < DDIM; ++d) x[d] = xin[(size_t)d * HW];
    // Pin x in VGPRs: opaque identity asm. Without this, LLVM rematerializes
    // the loop-invariant loads INSIDE the k-loop (r5: VGPR=40, VMEM-bound).
    #pragma unroll
    for (int d = 0; d < DDIM; ++d) __asm__ volatile("" : "+v"(x[d]));

    const float A = np_pairwise_sumsq64(x);

    // Scan this wave's 256-code slice; e-row address is wave-uniform =>
    // scalar loads (SMEM pipe) feeding v_fma with the SGPR operand.
    // Sequential fp32 FMA chain over d (bit-exact sgemm microkernel order).
    const int    k0 = wave * 256;
    const float* eb = emb + (size_t)k0 * DDIM;
    float best = 3.0e38f;
    int   bi   = k0;

    #pragma unroll 1
    for (int k = 0; k < 256; ++k) {
        const float* er = eb + (size_t)k * DDIM;   // uniform
        float g = 0.f;
        #pragma unroll
        for (int d = 0; d < DDIM; ++d) g = fmaf(x[d], er[d], g);
        float dk = __fadd_rn(__fsub_rn(A, __fmul_rn(2.0f, g)), cws[k0 + k]);
        if (dk < best) { best = dk; bi = k0 + k; }  // strict < => first-min
    }

    rbest[tid] = best;
    rbi[tid]   = bi;
    __syncthreads();

    // Wave 0 finishes its 64 points entirely in-register (x[] static indices).
    float lacc = 0.f;
    if (wave == 0) {
        // combine 4 slice winners; ascending slice + strict < == np first-min
        float bb = rbest[lane];
        int   ii = rbi[lane];
        #pragma unroll
        for (int s = 1; s < 4; ++s) {
            float c = rbest[s * 64 + lane];
            if (c < bb) { bb = c; ii = rbi[s * 64 + lane]; }
        }
        out[OUT_IDX + n] = (float)ii;

        // gather winning code row (per-lane scattered, codebook is L1/L2-hot)
        float q[DDIM];
        const float4* q4 = (const float4*)(emb + (size_t)ii * DDIM);
        #pragma unroll
        for (int j = 0; j < 16; ++j) ((float4*)q)[j] = q4[j];

        float* orow = out + OUT_Q + (size_t)b * DDIM * HW + hw;
        #pragma unroll
        for (int d = 0; d < DDIM; ++d) {
            float diff = __fsub_rn(q[d], x[d]);
            orow[(size_t)d * HW] = __fadd_rn(x[d], diff);   // ref's x + (q-x)
            lacc = fmaf(diff, diff, lacc);
        }
        #pragma unroll
        for (int off = 32; off > 0; off >>= 1) lacc += __shfl_down(lacc, off, 64);
    }

    if (tid == 0) {
        atomicAdd(loss_acc, lacc);
        __threadfence();
        unsigned old = atomicAdd(ticket, 1u);
        if (old == (unsigned)(nblocks - 1)) {             // last block
            __threadfence();
            float L = __hip_atomic_load(loss_acc, __ATOMIC_RELAXED,
                                        __HIP_MEMORY_SCOPE_AGENT);
            out[OUT_LOSS] = L * (1.25f / 4194304.0f);     // (1+CC)*mean
            out[OUT_NLL]  = 1.0f;
        }
    }
}

extern "C" void kernel_launch(void* const* d_in, const int* in_sizes, int n_in,
                              void* d_out, int out_size, void* d_ws, size_t ws_size,
                              hipStream_t stream) {
    const float* inp = (const float*)d_in[0];
    const float* emb = (const float*)d_in[1];
    float* out = (float*)d_out;
    float* ws  = (float*)d_ws;

    const int nblocks = NPTS / 64;   // 1024
    vq_pre<<<4, 256, 0, stream>>>(emb, ws);
    vq_main<<<nblocks, 256, 0, stream>>>(inp, emb, ws, ws + KCODES,
                                         (unsigned*)(ws + KCODES + 1), out,
                                         nblocks);
}